// Round 1
// baseline (622.483 us; speedup 1.0000x reference)
//
#include <hip/hip_runtime.h>

// ThreeStateExplorer: B=256 particles, T=100k steps.
//   k[t]   = inclusive cumsum(states==2)
//   vel[t] = (states[t]==2 ? 0 : e0s[b,k[t]] * (states[t]==0 ? sp0 : sp1))
//   X[t]   = x0 + DT * cumsum(vel)
// One block per particle; chunked hierarchical block scan.

#define NT    1024          // threads per block (16 waves)
#define IPT   8             // elements per thread per chunk
#define CHUNK (NT * IPT)    // 8192
#define NW    (NT / 64)     // 16 waves
#define SLOT  25            // 24 floats + 1 pad -> stride 25 % 32: conflict-free

__global__ __launch_bounds__(NT)
void traj_kernel(const int*   __restrict__ states,   // (B,T)
                 const float* __restrict__ e0s,      // (B,T+1,3)
                 const float* __restrict__ sp0v,     // (B,)
                 const float* __restrict__ sp1v,     // (B,)
                 const float* __restrict__ x0,       // (B,3)
                 float*       __restrict__ X,        // (B,T,3)
                 int T)
{
    const int b    = blockIdx.x;
    const int tid  = threadIdx.x;
    const int lane = tid & 63;
    const int wid  = tid >> 6;

    __shared__ float s_out[NT * SLOT];    // 100 KB staging, padded per-thread slots
    __shared__ int   s_wi[NW];
    __shared__ float s_wf[NW][3];

    const int*   st = states + (size_t)b * T;
    const float* er = e0s    + (size_t)b * (T + 1) * 3;
    float*       xr = X      + (size_t)b * T * 3;
    const float sp0 = sp0v[b], sp1 = sp1v[b];
    const float x00 = x0[3 * b + 0], x01 = x0[3 * b + 1], x02 = x0[3 * b + 2];

    int   kc  = 0;                        // tumble-count carry
    float pcx = 0.f, pcy = 0.f, pcz = 0.f; // position carry (un-scaled vel sum)

    for (int base = 0; base < T; base += CHUNK) {
        // ---- a) per-thread contiguous load of IPT states (2x int4, 32B aligned)
        int my[IPT];
        const int e0i = base + tid * IPT;
        if (e0i + IPT <= T) {
            int4 a = *(const int4*)(st + e0i);
            int4 c4 = *(const int4*)(st + e0i + 4);
            my[0] = a.x;  my[1] = a.y;  my[2] = a.z;  my[3] = a.w;
            my[4] = c4.x; my[5] = c4.y; my[6] = c4.z; my[7] = c4.w;
        } else {
            #pragma unroll
            for (int j = 0; j < IPT; ++j)
                my[j] = (e0i + j < T) ? st[e0i + j] : 3;   // sentinel 3: vel=0, not a tumble
        }

        // ---- b) tumble count -> block exclusive scan (int)
        int c = 0;
        #pragma unroll
        for (int j = 0; j < IPT; ++j) c += (my[j] == 2);
        int incl = c;
        #pragma unroll
        for (int d = 1; d < 64; d <<= 1) {
            int n = __shfl_up(incl, d, 64);
            if (lane >= d) incl += n;
        }
        if (lane == 63) s_wi[wid] = incl;
        __syncthreads();                                   // barrier 1
        int wex = 0, btot = 0;
        #pragma unroll
        for (int w = 0; w < NW; ++w) {
            int t = s_wi[w];
            wex  += (w < wid) ? t : 0;
            btot += t;
        }
        int k = kc + wex + (incl - c);   // tumbles strictly before my first element

        // ---- c) velocities + thread-local inclusive prefix
        float plx[IPT], ply[IPT], plz[IPT];
        float px = 0.f, py = 0.f, pz = 0.f;
        #pragma unroll
        for (int j = 0; j < IPT; ++j) {
            const int s = my[j];
            k += (s == 2);               // inclusive count; sp=0 at tumble so gather harmless
            const float sp = (s == 0) ? sp0 : ((s == 1) ? sp1 : 0.f);
            const float* e = er + (size_t)k * 3;   // k <= T always in bounds (e0s has T+1)
            px += e[0] * sp;
            py += e[1] * sp;
            pz += e[2] * sp;
            plx[j] = px; ply[j] = py; plz[j] = pz;
        }

        // ---- d) block exclusive scan (float3) of thread totals
        float ix = px, iy = py, iz = pz;
        #pragma unroll
        for (int d = 1; d < 64; d <<= 1) {
            float nx = __shfl_up(ix, d, 64);
            float ny = __shfl_up(iy, d, 64);
            float nz = __shfl_up(iz, d, 64);
            if (lane >= d) { ix += nx; iy += ny; iz += nz; }
        }
        if (lane == 63) { s_wf[wid][0] = ix; s_wf[wid][1] = iy; s_wf[wid][2] = iz; }
        __syncthreads();                                   // barrier 2
        float wfx = 0.f, wfy = 0.f, wfz = 0.f, btx = 0.f, bty = 0.f, btz = 0.f;
        #pragma unroll
        for (int w = 0; w < NW; ++w) {
            float tx = s_wf[w][0], ty = s_wf[w][1], tz = s_wf[w][2];
            if (w < wid) { wfx += tx; wfy += ty; wfz += tz; }
            btx += tx; bty += ty; btz += tz;
        }
        const float bx = pcx + wfx + (ix - px);
        const float by = pcy + wfy + (iy - py);
        const float bz = pcz + wfz + (iz - pz);

        // ---- e) positions -> padded LDS slot (stride 25: 2 lanes/bank, free)
        float* o = s_out + tid * SLOT;
        #pragma unroll
        for (int j = 0; j < IPT; ++j) {
            o[3 * j + 0] = x00 + (bx + plx[j]) * 0.1f;
            o[3 * j + 1] = x01 + (by + ply[j]) * 0.1f;
            o[3 * j + 2] = x02 + (bz + plz[j]) * 0.1f;
        }
        __syncthreads();                                   // barrier 3

        // ---- f) coalesced store: float f of chunk lives at LDS idx f + f/24
        const int rem = T - base;
        const int cnt = rem < CHUNK ? rem : CHUNK;
        float* dst = xr + (size_t)base * 3;
        if (cnt == CHUNK) {
            #pragma unroll
            for (int j = 0; j < IPT * 3; ++j) {
                const int f = tid + j * NT;
                dst[f] = s_out[f + f / 24];
            }
        } else {
            const int nfl = cnt * 3;
            for (int f = tid; f < nfl; f += NT)
                dst[f] = s_out[f + f / 24];
        }

        // ---- g) carries (uniform across all threads; no extra barrier needed:
        // next iteration's first shared write (s_wi) is after barrier 1, and all
        // readers of this iteration's buffers finish before reaching it.
        kc  += btot;
        pcx += btx; pcy += bty; pcz += btz;
    }
}

extern "C" void kernel_launch(void* const* d_in, const int* in_sizes, int n_in,
                              void* d_out, int out_size, void* d_ws, size_t ws_size,
                              hipStream_t stream) {
    const int*   states = (const int*)  d_in[0];
    const float* e0s    = (const float*)d_in[1];
    const float* sp0    = (const float*)d_in[2];
    const float* sp1    = (const float*)d_in[3];
    const float* x0     = (const float*)d_in[4];
    float*       X      = (float*)d_out;

    const int B = in_sizes[2];            // speed_0 has one entry per particle
    const int T = in_sizes[0] / B;        // states is (B,T)

    traj_kernel<<<dim3(B), dim3(NT), 0, stream>>>(states, e0s, sp0, sp1, x0, X, T);
}

// Round 2
// 594.217 us; speedup vs baseline: 1.0476x; 1.0476x over previous
//
#include <hip/hip_runtime.h>

// ThreeStateExplorer: B=256 particles, T=100k steps.
//   k[t]   = inclusive cumsum(states==2)
//   vel[t] = (states[t]==2 ? 0 : e0s[b,k[t]] * (states[t]==0 ? sp0 : sp1))
//   X[t]   = x0 + DT * cumsum(vel)
// One block per particle (grid 256 = CU count). Chunked hierarchical scan.
// R2: no LDS staging — direct float4 stores (each thread owns 96 contiguous
// bytes of X); 2 barriers/chunk; next-chunk states prefetched; gathers batched.

#define NT    1024          // threads per block (16 waves)
#define IPT   8             // elements per thread per chunk
#define CHUNK (NT * IPT)    // 8192
#define NW    (NT / 64)     // 16 waves

__device__ __forceinline__ void load_states(const int* __restrict__ st, int T,
                                            int e0i, int out[IPT]) {
    if (e0i + IPT <= T) {
        int4 a = *(const int4*)(st + e0i);
        int4 b = *(const int4*)(st + e0i + 4);
        out[0] = a.x; out[1] = a.y; out[2] = a.z; out[3] = a.w;
        out[4] = b.x; out[5] = b.y; out[6] = b.z; out[7] = b.w;
    } else {
        #pragma unroll
        for (int j = 0; j < IPT; ++j)
            out[j] = (e0i + j < T) ? st[e0i + j] : 3;  // sentinel: vel=0, no tumble
    }
}

__global__ __launch_bounds__(NT)
void traj_kernel(const int*   __restrict__ states,   // (B,T)
                 const float* __restrict__ e0s,      // (B,T+1,3)
                 const float* __restrict__ sp0v,     // (B,)
                 const float* __restrict__ sp1v,     // (B,)
                 const float* __restrict__ x0,       // (B,3)
                 float*       __restrict__ X,        // (B,T,3)
                 int T)
{
    const int b    = blockIdx.x;
    const int tid  = threadIdx.x;
    const int lane = tid & 63;
    const int wid  = tid >> 6;

    __shared__ int   s_wi[NW];
    __shared__ float s_wf[NW][3];

    const int*   st = states + (size_t)b * T;
    const float* er = e0s    + (size_t)b * (T + 1) * 3;
    float*       xr = X      + (size_t)b * T * 3;
    const float sp0 = sp0v[b], sp1 = sp1v[b];
    const float x00 = x0[3 * b + 0], x01 = x0[3 * b + 1], x02 = x0[3 * b + 2];

    int   kc  = 0;                          // tumble-count carry
    float pcx = 0.f, pcy = 0.f, pcz = 0.f;  // position carry (un-scaled vel sum)

    int cur[IPT];
    load_states(st, T, tid * IPT, cur);

    for (int base = 0; base < T; base += CHUNK) {
        // ---- prefetch next chunk's states (in flight under this chunk's work)
        int nxt[IPT];
        const bool has_next = (base + CHUNK) < T;   // wave-uniform
        if (has_next) load_states(st, T, base + CHUNK + tid * IPT, nxt);

        // ---- tumble-count block scan
        int c = 0;
        #pragma unroll
        for (int j = 0; j < IPT; ++j) c += (cur[j] == 2);
        int incl = c;
        #pragma unroll
        for (int d = 1; d < 64; d <<= 1) {
            int n = __shfl_up(incl, d, 64);
            if (lane >= d) incl += n;
        }
        if (lane == 63) s_wi[wid] = incl;
        __syncthreads();                                   // barrier 1
        int wex = 0, btot = 0;
        #pragma unroll
        for (int w = 0; w < NW; ++w) {
            int t = s_wi[w];
            wex  += (w < wid) ? t : 0;
            btot += t;
        }
        int k = kc + wex + (incl - c);    // tumbles strictly before my 1st elem

        // ---- batched gathers (addresses all known now; loads issue together)
        float ex[IPT], ey[IPT], ez[IPT];
        #pragma unroll
        for (int j = 0; j < IPT; ++j) {
            const int s = cur[j];
            k += (s == 2);                // inclusive count; sp=0 at tumble
            const float sp = (s == 0) ? sp0 : ((s == 1) ? sp1 : 0.f);
            const float* e = er + (size_t)k * 3;   // k <= T: always in bounds
            ex[j] = e[0] * sp;
            ey[j] = e[1] * sp;
            ez[j] = e[2] * sp;
        }

        // ---- thread-local inclusive prefix (into output-layout array)
        float o[IPT * 3];
        float px = 0.f, py = 0.f, pz = 0.f;
        #pragma unroll
        for (int j = 0; j < IPT; ++j) {
            px += ex[j]; py += ey[j]; pz += ez[j];
            o[3 * j + 0] = px; o[3 * j + 1] = py; o[3 * j + 2] = pz;
        }

        // ---- block scan (float3) of thread totals
        float ix = px, iy = py, iz = pz;
        #pragma unroll
        for (int d = 1; d < 64; d <<= 1) {
            float nx = __shfl_up(ix, d, 64);
            float ny = __shfl_up(iy, d, 64);
            float nz = __shfl_up(iz, d, 64);
            if (lane >= d) { ix += nx; iy += ny; iz += nz; }
        }
        if (lane == 63) { s_wf[wid][0] = ix; s_wf[wid][1] = iy; s_wf[wid][2] = iz; }
        __syncthreads();                                   // barrier 2
        float wfx = 0.f, wfy = 0.f, wfz = 0.f, btx = 0.f, bty = 0.f, btz = 0.f;
        #pragma unroll
        for (int w = 0; w < NW; ++w) {
            float tx = s_wf[w][0], ty = s_wf[w][1], tz = s_wf[w][2];
            if (w < wid) { wfx += tx; wfy += ty; wfz += tz; }
            btx += tx; bty += ty; btz += tz;
        }
        const float bx = pcx + wfx + (ix - px);
        const float by = pcy + wfy + (iy - py);
        const float bz = pcz + wfz + (iz - pz);

        // ---- finalize positions in place, store direct (96 B contiguous/thread)
        #pragma unroll
        for (int j = 0; j < IPT; ++j) {
            o[3 * j + 0] = x00 + (bx + o[3 * j + 0]) * 0.1f;
            o[3 * j + 1] = x01 + (by + o[3 * j + 1]) * 0.1f;
            o[3 * j + 2] = x02 + (bz + o[3 * j + 2]) * 0.1f;
        }
        const int e0i = base + tid * IPT;
        if (e0i + IPT <= T) {
            float4* d4 = (float4*)(xr + (size_t)e0i * 3);  // 96 B offset: 16B-aligned
            d4[0] = make_float4(o[0],  o[1],  o[2],  o[3]);
            d4[1] = make_float4(o[4],  o[5],  o[6],  o[7]);
            d4[2] = make_float4(o[8],  o[9],  o[10], o[11]);
            d4[3] = make_float4(o[12], o[13], o[14], o[15]);
            d4[4] = make_float4(o[16], o[17], o[18], o[19]);
            d4[5] = make_float4(o[20], o[21], o[22], o[23]);
        } else {
            #pragma unroll
            for (int j = 0; j < IPT; ++j)
                if (e0i + j < T) {
                    float* d = xr + (size_t)(e0i + j) * 3;
                    d[0] = o[3 * j + 0]; d[1] = o[3 * j + 1]; d[2] = o[3 * j + 2];
                }
        }

        // ---- carries (uniform; hazards covered: s_wi next write is after this
        // iter's B2; s_wf next write is after next iter's B1)
        kc  += btot;
        pcx += btx; pcy += bty; pcz += btz;

        #pragma unroll
        for (int j = 0; j < IPT; ++j) cur[j] = nxt[j];
    }
}

extern "C" void kernel_launch(void* const* d_in, const int* in_sizes, int n_in,
                              void* d_out, int out_size, void* d_ws, size_t ws_size,
                              hipStream_t stream) {
    const int*   states = (const int*)  d_in[0];
    const float* e0s    = (const float*)d_in[1];
    const float* sp0    = (const float*)d_in[2];
    const float* sp1    = (const float*)d_in[3];
    const float* x0     = (const float*)d_in[4];
    float*       X      = (float*)d_out;

    const int B = in_sizes[2];            // speed_0 has one entry per particle
    const int T = in_sizes[0] / B;        // states is (B,T)

    traj_kernel<<<dim3(B), dim3(NT), 0, stream>>>(states, e0s, sp0, sp1, x0, X, T);
}